// Round 1
// baseline (185.028 us; speedup 1.0000x reference)
//
#include <hip/hip_runtime.h>

#define HH 768
#define NN 64
#define LL 2048
#define BB 4
#define NCH 32           // number of chunks
#define UST 17           // u_buf float4-stride per chunk (68 floats, padded)

__device__ __forceinline__ float2 cmul2(float2 a, float2 b) {
    return make_float2(fmaf(a.x, b.x, -(a.y * b.y)), fmaf(a.x, b.y, a.y * b.x));
}

// s = A*s + u   (complex A,s ; real u)
__device__ __forceinline__ float2 astep(float2 A, float2 s, float uu) {
    return make_float2(fmaf(A.x, s.x, fmaf(-A.y, s.y, uu)),
                       fmaf(A.x, s.y, A.y * s.x));
}

__global__ __launch_bounds__(256) void ssm_kernel(
    const float* __restrict__ ug,
    const float* __restrict__ lnr,
    const float* __restrict__ img,
    const float* __restrict__ Brp,
    const float* __restrict__ Bip,
    const float* __restrict__ Crp,
    const float* __restrict__ Cip,
    const float* __restrict__ ldt,
    const float* __restrict__ Dp,
    float* __restrict__ outg)
{
    __shared__ __align__(16) float u_buf[NCH * 68];        // chunk-padded u row
    __shared__ __align__(16) float2 wbuf[NN][66];          // W[n][j]=CB*A^(j+1); [65]=CB
    __shared__ float2 xbuf[(NCH + 1) * 65];                // slot c = state x[c-1]; stride 65
    __shared__ float kpad[128];                            // [0..63]=0, [64+t]=K[t]
    __shared__ float2 albuf[NN];                           // A_bar
    __shared__ float2 cbbuf[NN];                           // C*B_bar

    const int tid = threadIdx.x;
    const int h = blockIdx.x % HH;
    const int b = blockIdx.x / HH;

    const float dt = expf(ldt[h]);
    const float Dh = Dp[h];
    const float* urow = ug + (size_t)(b * HH + h) * LL;

    // ---- phase 0: per-state params (one lane per n) ----
    if (tid < NN) {
        const int n = tid;
        const float lre = -expf(lnr[h * NN + n]);
        const float lim = img[h * NN + n];
        const float e = expf(lre * dt);
        const float th = lim * dt;
        const float2 A = make_float2(e * cosf(th), e * sinf(th));
        // B_bar = (A-1) * (1/Lambda) * B
        const float den = lre * lre + lim * lim;
        const float2 invL = make_float2(lre / den, -lim / den);
        const float2 am1 = make_float2(A.x - 1.0f, A.y);
        const float2 t1 = cmul2(am1, invL);
        const float2 Bb = cmul2(t1, make_float2(Brp[h * NN + n], Bip[h * NN + n]));
        const float2 CB = cmul2(make_float2(Crp[h * NN + n], Cip[h * NN + n]), Bb);
        albuf[n] = A;
        cbbuf[n] = CB;
        wbuf[n][65] = CB;                       // CB*A^0 for K[0]
        xbuf[n] = make_float2(0.f, 0.f);        // slot 0 = x[-1] = 0
        kpad[n] = 0.f;                          // zero pad of K
    }
    // ---- phase 0b: stage u into padded LDS ----
    {
        const float4* u4g = (const float4*)urow;
        float4* u4s = (float4*)u_buf;
        const int cA = tid >> 4, kA = tid & 15;
        u4s[cA * UST + kA] = u4g[tid];
        u4s[(cA + 16) * UST + kA] = u4g[tid + 256];
    }
    __syncthreads();

    const int n = tid & 63;
    const int q = tid >> 6;

    // ---- phase 1: W table, W[n][j] = CB * A^(j+1), j in [16q,16q+16) ----
    {
        const float2 A = albuf[n];
        float2 a2 = cmul2(A, A);
        float2 a4 = cmul2(a2, a2);
        float2 a8 = cmul2(a4, a4);
        float2 a16 = cmul2(a8, a8);
        float2 p = cmul2(cbbuf[n], A);
        for (int i = 0; i < q; ++i) p = cmul2(p, a16);
        #pragma unroll
        for (int k = 0; k < 16; ++k) {
            wbuf[n][16 * q + k] = p;
            p = cmul2(p, A);
        }
    }
    // ---- phase 2: chunk input sums S[c][n] (Horner), to xbuf slot c+1 ----
    {
        const float2 A = albuf[n];
        const float4* u4 = (const float4*)u_buf;
        for (int c = q; c < NCH; c += 4) {
            float2 s = make_float2(0.f, 0.f);
            #pragma unroll 4
            for (int t4 = 0; t4 < 16; ++t4) {
                const float4 uu = u4[c * UST + t4];
                s = astep(A, s, uu.x);
                s = astep(A, s, uu.y);
                s = astep(A, s, uu.z);
                s = astep(A, s, uu.w);
            }
            xbuf[(c + 1) * 65 + n] = s;
        }
    }
    __syncthreads();

    if (q == 0) {
        // ---- K[t] = Re(sum_n CB*A^t) = sum_n wbuf[n][t-1].x  (t=0 -> [65]) ----
        const int idx = (n == 0) ? 65 : (n - 1);
        float acc = 0.f;
        #pragma unroll 8
        for (int nn = 0; nn < NN; ++nn) acc += wbuf[nn][idx].x;
        kpad[64 + n] = acc;
    } else if (q == 1) {
        // ---- scan over chunks: x[c] = A^64 x[c-1] + S[c] ----
        const float2 A = albuf[n];
        float2 a2 = cmul2(A, A);
        float2 a4 = cmul2(a2, a2);
        float2 a8 = cmul2(a4, a4);
        float2 a16 = cmul2(a8, a8);
        float2 a32 = cmul2(a16, a16);
        float2 a64 = cmul2(a32, a32);
        float2 x = make_float2(0.f, 0.f);
        for (int c = 0; c < NCH; ++c) {
            const float2 s = xbuf[(c + 1) * 65 + n];
            x = make_float2(fmaf(a64.x, x.x, fmaf(-a64.y, x.y, s.x)),
                            fmaf(a64.x, x.y, fmaf(a64.y, x.x, s.y)));
            xbuf[(c + 1) * 65 + n] = x;
        }
    }
    __syncthreads();

    // ---- phase 4: outputs. thread = 4 consecutive j x 2 chunks ----
    const int jt = tid & 15;       // j0 = 4*jt
    const int ct = tid >> 4;       // c0 = ct, c1 = ct+16
    const int c0 = ct, c1 = ct + 16;

    float a00 = 0.f, a01 = 0.f, a02 = 0.f, a03 = 0.f;
    float a10 = 0.f, a11 = 0.f, a12 = 0.f, a13 = 0.f;

    // boundary: acc[k][i] += Re( W[n][4jt+k] * x[c_i - 1] )
    {
        const float4* w4 = (const float4*)&wbuf[0][0];   // row stride 33 float4
        #pragma unroll 4
        for (int nn = 0; nn < NN; ++nn) {
            const float4 wA = w4[nn * 33 + 2 * jt];      // j = 4jt, 4jt+1 (re,im pairs)
            const float4 wB = w4[nn * 33 + 2 * jt + 1];  // j = 4jt+2, 4jt+3
            const float2 x0 = xbuf[c0 * 65 + nn];
            const float2 x1 = xbuf[c1 * 65 + nn];
            a00 = fmaf(wA.x, x0.x, fmaf(-wA.y, x0.y, a00));
            a01 = fmaf(wA.z, x0.x, fmaf(-wA.w, x0.y, a01));
            a02 = fmaf(wB.x, x0.x, fmaf(-wB.y, x0.y, a02));
            a03 = fmaf(wB.z, x0.x, fmaf(-wB.w, x0.y, a03));
            a10 = fmaf(wA.x, x1.x, fmaf(-wA.y, x1.y, a10));
            a11 = fmaf(wA.z, x1.x, fmaf(-wA.w, x1.y, a11));
            a12 = fmaf(wB.x, x1.x, fmaf(-wB.y, x1.y, a12));
            a13 = fmaf(wB.z, x1.x, fmaf(-wB.w, x1.y, a13));
        }
    }
    // intra-chunk conv: acc[k][i] += K[4jt+k-s] * u[c_i*64+s]  (K zero-padded)
    {
        const float4* u4 = (const float4*)u_buf;
        const int kbase = 64 + 4 * jt;
        #pragma unroll 4
        for (int s4 = 0; s4 < 16; ++s4) {
            const float4 ua = u4[c0 * UST + s4];
            const float4 ub = u4[c1 * UST + s4];
            #pragma unroll
            for (int ds = 0; ds < 4; ++ds) {
                const int kb = kbase - (4 * s4 + ds);
                const float k0 = kpad[kb];
                const float k1 = kpad[kb + 1];
                const float k2 = kpad[kb + 2];
                const float k3 = kpad[kb + 3];
                const float us0 = (ds == 0) ? ua.x : (ds == 1) ? ua.y : (ds == 2) ? ua.z : ua.w;
                const float us1 = (ds == 0) ? ub.x : (ds == 1) ? ub.y : (ds == 2) ? ub.z : ub.w;
                a00 = fmaf(k0, us0, a00);
                a01 = fmaf(k1, us0, a01);
                a02 = fmaf(k2, us0, a02);
                a03 = fmaf(k3, us0, a03);
                a10 = fmaf(k0, us1, a10);
                a11 = fmaf(k1, us1, a11);
                a12 = fmaf(k2, us1, a12);
                a13 = fmaf(k3, us1, a13);
            }
        }
    }
    // epilogue: + D*u, store
    {
        const float4* u4 = (const float4*)u_buf;
        const float4 uA = u4[c0 * UST + jt];
        const float4 uB = u4[c1 * UST + jt];
        float4* o4 = (float4*)(outg + (size_t)(b * HH + h) * LL);
        o4[c0 * 16 + jt] = make_float4(fmaf(Dh, uA.x, a00), fmaf(Dh, uA.y, a01),
                                       fmaf(Dh, uA.z, a02), fmaf(Dh, uA.w, a03));
        o4[c1 * 16 + jt] = make_float4(fmaf(Dh, uB.x, a10), fmaf(Dh, uB.y, a11),
                                       fmaf(Dh, uB.z, a12), fmaf(Dh, uB.w, a13));
    }
}

extern "C" void kernel_launch(void* const* d_in, const int* in_sizes, int n_in,
                              void* d_out, int out_size, void* d_ws, size_t ws_size,
                              hipStream_t stream) {
    (void)in_sizes; (void)n_in; (void)out_size; (void)d_ws; (void)ws_size;
    ssm_kernel<<<dim3(BB * HH), dim3(256), 0, stream>>>(
        (const float*)d_in[0], (const float*)d_in[1], (const float*)d_in[2],
        (const float*)d_in[3], (const float*)d_in[4], (const float*)d_in[5],
        (const float*)d_in[6], (const float*)d_in[7], (const float*)d_in[8],
        (float*)d_out);
}

// Round 6
// 163.524 us; speedup vs baseline: 1.1315x; 1.1315x over previous
//
#include <hip/hip_runtime.h>

#define HH 768
#define NN 64
#define LL 2048
#define BB 4

// POOL byte offsets (16-aligned). Word-strides chosen ≡ 2 or 4 (mod 32) so the
// worst LDS aliasing is 2-way (free, m136).
#define UF_OFF 0        // u fp32: 32 chunk-rows x 68 floats = 8704 B
#define WB_OFF 8704     // W packed (re,im) bf16: 64 n-rows x 68 uints = 17408 B
#define SZ_OFF 26112    // fp32 scratch(64x66) / S,x(32x132) = 16896 B
#define KP_OFF 43008    // kpad: 128 floats ([0..63]=0, [64+t]=K[t]) = 512 B
#define AB_OFF 43520    // Abar: 64 float2 = 512 B
#define CB_OFF 44032    // CBb:  64 float2 = 512 B
#define POOL_SZ 44544   // 43.5 KB -> 3 blocks/CU

__device__ __forceinline__ float2 cmul(float2 a, float2 b) {
    return make_float2(fmaf(a.x, b.x, -(a.y * b.y)), fmaf(a.x, b.y, a.y * b.x));
}
// acc += a*b (complex)
__device__ __forceinline__ float2 cfma(float2 a, float2 b, float2 acc) {
    acc.x = fmaf(a.x, b.x, fmaf(-a.y, b.y, acc.x));
    acc.y = fmaf(a.x, b.y, fmaf(a.y, b.x, acc.y));
    return acc;
}
// s = A*s + u (complex A,s; real u)
__device__ __forceinline__ float2 astep(float2 A, float2 s, float uu) {
    return make_float2(fmaf(A.x, s.x, fmaf(-A.y, s.y, uu)),
                       fmaf(A.x, s.y, A.y * s.x));
}
__device__ __forceinline__ unsigned short f2bf(float x) {   // RNE float->bf16
    union { float f; unsigned u; } v; v.f = x;
    return (unsigned short)((v.u + 0x7fffu + ((v.u >> 16) & 1u)) >> 16);
}
__device__ __forceinline__ float lo2f(unsigned v) {   // low16 bf16 -> float
    union { unsigned u; float f; } x; x.u = v << 16; return x.f;
}
__device__ __forceinline__ float hi2f(unsigned v) {   // high16 bf16 -> float
    union { unsigned u; float f; } x; x.u = v & 0xffff0000u; return x.f;
}

__global__ __launch_bounds__(256, 3) void ssm_kernel6(
    const float* __restrict__ ug,
    const float* __restrict__ lnr,
    const float* __restrict__ img,
    const float* __restrict__ Brp,
    const float* __restrict__ Bip,
    const float* __restrict__ Crp,
    const float* __restrict__ Cip,
    const float* __restrict__ ldt,
    const float* __restrict__ Dp,
    float* __restrict__ outg)
{
    __shared__ __align__(16) unsigned char POOL[POOL_SZ];
    float*        UF   = (float*)(POOL + UF_OFF);
    unsigned int* WB   = (unsigned int*)(POOL + WB_OFF);
    float*        SZ   = (float*)(POOL + SZ_OFF);   // scratch view: [j*66+n]; S/x view: [c*132 + n | +64+n]
    float*        kpad = (float*)(POOL + KP_OFF);
    float2*       Abar = (float2*)(POOL + AB_OFF);
    float2*       CBb  = (float2*)(POOL + CB_OFF);

    const int tid = threadIdx.x;
    const int h = blockIdx.x % HH;
    const int b = blockIdx.x / HH;
    const int lane = tid & 63;
    const int w = tid >> 6;

    const float dt = expf(ldt[h]);
    const float Dh = Dp[h];

    // ---- P0: per-state params (r1-proven) + kpad zero pad ----
    if (tid < NN) {
        const int n = tid;
        const float lre = -expf(lnr[h * NN + n]);
        const float lim = img[h * NN + n];
        const float e = expf(lre * dt);
        const float th = lim * dt;
        const float2 A = make_float2(e * cosf(th), e * sinf(th));
        const float den = lre * lre + lim * lim;
        const float2 invL = make_float2(lre / den, -lim / den);
        const float2 am1 = make_float2(A.x - 1.0f, A.y);
        const float2 Bb = cmul(cmul(am1, invL), make_float2(Brp[h*NN+n], Bip[h*NN+n]));
        const float2 CB = cmul(make_float2(Crp[h*NN+n], Cip[h*NN+n]), Bb);
        Abar[n] = A;
        CBb[n] = CB;
        kpad[n] = 0.f;
    }
    // ---- P0b: stage u fp32 chunk-padded (r1-proven) ----
    {
        const float4* u4g = (const float4*)(ug + (size_t)(b * HH + h) * LL);
        float4* uf4 = (float4*)UF;
        #pragma unroll
        for (int r = 0; r < 2; ++r) {
            const int i = tid + 256 * r;
            uf4[(i >> 4) * 17 + (i & 15)] = u4g[i];
        }
    }
    __syncthreads();   // b0

    // ---- P1: W table (packed bf16 pairs) + fp32 Re-plane scratch for exact K ----
    // W[n][j] = CB_n * A_n^(j+1); thread (lane=n, wave w) covers j in [16w,16w+16)
    {
        const float2 A = Abar[lane];
        const float2 a2 = cmul(A, A), a4 = cmul(a2, a2), a8 = cmul(a4, a4), a16 = cmul(a8, a8);
        float2 pw = cmul(CBb[lane], A);
        for (int i = 0; i < w; ++i) pw = cmul(pw, a16);
        #pragma unroll
        for (int jj = 0; jj < 16; ++jj) {
            const int j = 16 * w + jj;
            WB[lane * 68 + j] = (unsigned)f2bf(pw.x) | ((unsigned)f2bf(pw.y) << 16);
            SZ[j * 66 + lane] = pw.x;   // fp32 Re(CB*A^(j+1)) scratch
            pw = cmul(pw, A);
        }
    }
    __syncthreads();   // b1

    // ---- P2a: exact K (wave 0): K[t] = sum_n Re(CB A^t); t>=1 from scratch row t-1 ----
    if (w == 0) {
        float acc = 0.f;
        if (lane == 0) {
            for (int n = 0; n < NN; ++n) acc += CBb[n].x;
        } else {
            const float* row = &SZ[(lane - 1) * 66];
            #pragma unroll 8
            for (int n = 0; n < NN; ++n) acc += row[n];
        }
        kpad[64 + lane] = acc;
    }
    // ---- P2b: two-level Horner encode into REGISTERS (all waves) ----
    // S[c]_n = sum_t A^(63-t) u[c*64+t]; 8 independent 8-step chains + A^8k recombine
    float2 Sres[8];
    {
        const float2 A = Abar[lane];
        const float2 p2 = cmul(A, A), p4 = cmul(p2, p2), p8 = cmul(p4, p4);
        float2 P8[8];
        P8[0] = make_float2(1.f, 0.f);
        #pragma unroll
        for (int k = 1; k < 8; ++k) P8[k] = cmul(P8[k-1], p8);
        const float4* uf4 = (const float4*)UF;
        #pragma unroll
        for (int k8 = 0; k8 < 8; ++k8) {
            const int c = w + 4 * k8;
            float2 sg[8];
            #pragma unroll
            for (int g = 0; g < 8; ++g) {
                const float4 ua = uf4[c * 17 + 2 * g];
                const float4 ub = uf4[c * 17 + 2 * g + 1];
                float2 s = make_float2(ua.x, 0.f);
                s = astep(A, s, ua.y);
                s = astep(A, s, ua.z);
                s = astep(A, s, ua.w);
                s = astep(A, s, ub.x);
                s = astep(A, s, ub.y);
                s = astep(A, s, ub.z);
                s = astep(A, s, ub.w);
                sg[g] = s;
            }
            float2 S = sg[7];
            #pragma unroll
            for (int g = 0; g < 7; ++g) S = cfma(P8[7 - g], sg[g], S);
            Sres[k8] = S;
        }
    }
    __syncthreads();   // b2 (scratch reads done)

    // ---- P3: write S to SZ (S/x view) ----
    #pragma unroll
    for (int k8 = 0; k8 < 8; ++k8) {
        const int c = w + 4 * k8;
        SZ[c * 132 + lane]      = Sres[k8].x;
        SZ[c * 132 + 64 + lane] = Sres[k8].y;
    }
    __syncthreads();   // b3

    // ---- P4a: scan (wave 0), fp32, in place: SZ[c] := x[c-1] (r1-proven math) ----
    if (w == 0) {
        const float2 A = Abar[lane];
        const float2 a2 = cmul(A, A), a4 = cmul(a2, a2), a8 = cmul(a4, a4),
                     a16 = cmul(a8, a8), a32 = cmul(a16, a16), a64 = cmul(a32, a32);
        float xr = 0.f, xi = 0.f;
        for (int c = 0; c < 32; ++c) {
            const float sr = SZ[c * 132 + lane];
            const float si = SZ[c * 132 + 64 + lane];
            SZ[c * 132 + lane]      = xr;
            SZ[c * 132 + 64 + lane] = xi;
            const float nxr = fmaf(a64.x, xr, fmaf(-a64.y, xi, sr));
            xi = fmaf(a64.x, xi, fmaf(a64.y, xr, si));
            xr = nxr;
        }
    }
    // ---- P4b: conv (all waves, scan-independent): r1 math + register k-windows ----
    const int jt = tid & 15;        // j0 = 4*jt
    const int ct = tid >> 4;        // c0 = ct, c1 = ct+16
    const int c0 = ct, c1 = ct + 16;
    float a00 = 0.f, a01 = 0.f, a02 = 0.f, a03 = 0.f;
    float a10 = 0.f, a11 = 0.f, a12 = 0.f, a13 = 0.f;
    {
        const float4* u4 = (const float4*)UF;
        const float4* kp4 = (const float4*)kpad;
        #pragma unroll 4
        for (int s4 = 0; s4 < 16; ++s4) {
            const float4 ua = u4[c0 * 17 + s4];
            const float4 ub = u4[c1 * 17 + s4];
            const float4 Av = kp4[15 + jt - s4];   // kpad[K0-4 .. K0-1], K0 = 64+4jt-4s4
            const float4 Bv = kp4[16 + jt - s4];   // kpad[K0   .. K0+3]
            // ds=0
            a00 = fmaf(Bv.x, ua.x, a00); a01 = fmaf(Bv.y, ua.x, a01);
            a02 = fmaf(Bv.z, ua.x, a02); a03 = fmaf(Bv.w, ua.x, a03);
            a10 = fmaf(Bv.x, ub.x, a10); a11 = fmaf(Bv.y, ub.x, a11);
            a12 = fmaf(Bv.z, ub.x, a12); a13 = fmaf(Bv.w, ub.x, a13);
            // ds=1
            a00 = fmaf(Av.w, ua.y, a00); a01 = fmaf(Bv.x, ua.y, a01);
            a02 = fmaf(Bv.y, ua.y, a02); a03 = fmaf(Bv.z, ua.y, a03);
            a10 = fmaf(Av.w, ub.y, a10); a11 = fmaf(Bv.x, ub.y, a11);
            a12 = fmaf(Bv.y, ub.y, a12); a13 = fmaf(Bv.z, ub.y, a13);
            // ds=2
            a00 = fmaf(Av.z, ua.z, a00); a01 = fmaf(Av.w, ua.z, a01);
            a02 = fmaf(Bv.x, ua.z, a02); a03 = fmaf(Bv.y, ua.z, a03);
            a10 = fmaf(Av.z, ub.z, a10); a11 = fmaf(Av.w, ub.z, a11);
            a12 = fmaf(Bv.x, ub.z, a12); a13 = fmaf(Bv.y, ub.z, a13);
            // ds=3
            a00 = fmaf(Av.y, ua.w, a00); a01 = fmaf(Av.z, ua.w, a01);
            a02 = fmaf(Av.w, ua.w, a02); a03 = fmaf(Bv.x, ua.w, a03);
            a10 = fmaf(Av.y, ub.w, a10); a11 = fmaf(Av.z, ub.w, a11);
            a12 = fmaf(Av.w, ub.w, a12); a13 = fmaf(Bv.x, ub.w, a13);
        }
    }
    __syncthreads();   // b4: x ready

    // ---- P5: boundary single-pass (packed bf16 W, fp32 x) + epilogue ----
    {
        #pragma unroll 8
        for (int n = 0; n < NN; ++n) {
            const uint4 wp = *(const uint4*)&WB[n * 68 + 4 * jt];  // (re,im) pairs j0..j0+3
            const float xr0 = SZ[c0 * 132 + n], xi0 = SZ[c0 * 132 + 64 + n];
            const float xr1 = SZ[c1 * 132 + n], xi1 = SZ[c1 * 132 + 64 + n];
            const float wr0 = lo2f(wp.x), wi0 = hi2f(wp.x);
            const float wr1 = lo2f(wp.y), wi1 = hi2f(wp.y);
            const float wr2 = lo2f(wp.z), wi2 = hi2f(wp.z);
            const float wr3 = lo2f(wp.w), wi3 = hi2f(wp.w);
            a00 = fmaf(wr0, xr0, fmaf(-wi0, xi0, a00));
            a01 = fmaf(wr1, xr0, fmaf(-wi1, xi0, a01));
            a02 = fmaf(wr2, xr0, fmaf(-wi2, xi0, a02));
            a03 = fmaf(wr3, xr0, fmaf(-wi3, xi0, a03));
            a10 = fmaf(wr0, xr1, fmaf(-wi0, xi1, a10));
            a11 = fmaf(wr1, xr1, fmaf(-wi1, xi1, a11));
            a12 = fmaf(wr2, xr1, fmaf(-wi2, xi1, a12));
            a13 = fmaf(wr3, xr1, fmaf(-wi3, xi1, a13));
        }
    }
    {
        const float4* u4 = (const float4*)UF;
        const float4 uA = u4[c0 * 17 + jt];
        const float4 uB = u4[c1 * 17 + jt];
        float4* o4 = (float4*)(outg + (size_t)(b * HH + h) * LL);
        o4[c0 * 16 + jt] = make_float4(fmaf(Dh, uA.x, a00), fmaf(Dh, uA.y, a01),
                                       fmaf(Dh, uA.z, a02), fmaf(Dh, uA.w, a03));
        o4[c1 * 16 + jt] = make_float4(fmaf(Dh, uB.x, a10), fmaf(Dh, uB.y, a11),
                                       fmaf(Dh, uB.z, a12), fmaf(Dh, uB.w, a13));
    }
}

extern "C" void kernel_launch(void* const* d_in, const int* in_sizes, int n_in,
                              void* d_out, int out_size, void* d_ws, size_t ws_size,
                              hipStream_t stream) {
    (void)in_sizes; (void)n_in; (void)out_size; (void)d_ws; (void)ws_size;
    ssm_kernel6<<<dim3(BB * HH), dim3(256), 0, stream>>>(
        (const float*)d_in[0], (const float*)d_in[1], (const float*)d_in[2],
        (const float*)d_in[3], (const float*)d_in[4], (const float*)d_in[5],
        (const float*)d_in[6], (const float*)d_in[7], (const float*)d_in[8],
        (float*)d_out);
}

// Round 7
// 152.239 us; speedup vs baseline: 1.2154x; 1.0741x over previous
//
#include <hip/hip_runtime.h>

#define HH 768
#define NN 64
#define LL 2048
#define BB 4

typedef __attribute__((ext_vector_type(2))) float f32x2;

// LDS pool offsets (16B aligned)
#define UF_OFF  0        // u fp32: 32 rows x 68 floats            = 8704 B
#define WRE_OFF 8704     // W real fp32: 64 rows x 68 floats       = 17408 B
#define WIM_OFF 26112    // W imag bf16-pairs: 64 rows x 33 uints  = 8448 B
#define SZ_OFF  34560    // fp32 S-then-x: 32 rows x 130 floats    = 16640 B
#define KP_OFF  51200    // kpad: 128 floats ([0..63]=0,[64+t]=K)  = 512 B
#define AB_OFF  51712    // Abar 64 float2
#define CB_OFF  52224    // CBb  64 float2
#define POOL_SZ 52736    // 51.5 KB -> 3 blocks/CU

__device__ __forceinline__ float2 cmul(float2 a, float2 b) {
    return make_float2(fmaf(a.x, b.x, -(a.y * b.y)), fmaf(a.x, b.y, a.y * b.x));
}
__device__ __forceinline__ unsigned short f2bf(float x) {   // RNE float->bf16
    union { float f; unsigned u; } v; v.f = x;
    return (unsigned short)((v.u + 0x7fffu + ((v.u >> 16) & 1u)) >> 16);
}
__device__ __forceinline__ float lo2f(unsigned v) {
    union { unsigned u; float f; } x; x.u = v << 16; return x.f;
}
__device__ __forceinline__ float hi2f(unsigned v) {
    union { unsigned u; float f; } x; x.u = v & 0xffff0000u; return x.f;
}
// packed helpers (target v_pk_fma_f32 / v_pk_mul_f32)
__device__ __forceinline__ f32x2 pkfma(f32x2 a, f32x2 b, f32x2 c) {
    return __builtin_elementwise_fma(a, b, c);
}
__device__ __forceinline__ f32x2 splat2(float x) { return (f32x2){x, x}; }
__device__ __forceinline__ f32x2 swapneg(f32x2 v) { return (f32x2){-v[1], v[0]}; }
// complex mul on packed (re,im)
__device__ __forceinline__ f32x2 cmul2(f32x2 a, f32x2 b) {
    return pkfma(splat2(a[0]), b, splat2(a[1]) * swapneg(b));
}

__global__ __launch_bounds__(256, 3) void ssm_kernel7(
    const float* __restrict__ ug,
    const float* __restrict__ lnr,
    const float* __restrict__ img,
    const float* __restrict__ Brp,
    const float* __restrict__ Bip,
    const float* __restrict__ Crp,
    const float* __restrict__ Cip,
    const float* __restrict__ ldt,
    const float* __restrict__ Dp,
    float* __restrict__ outg)
{
    __shared__ __align__(16) unsigned char POOL[POOL_SZ];
    float*        UF   = (float*)(POOL + UF_OFF);
    float*        WRE  = (float*)(POOL + WRE_OFF);
    unsigned int* WIM  = (unsigned int*)(POOL + WIM_OFF);
    float*        SZ   = (float*)(POOL + SZ_OFF);
    float*        kpad = (float*)(POOL + KP_OFF);
    float2*       Abar = (float2*)(POOL + AB_OFF);
    float2*       CBb  = (float2*)(POOL + CB_OFF);

    const int tid = threadIdx.x;
    const int h = blockIdx.x % HH;
    const int b = blockIdx.x / HH;
    const int lane = tid & 63;
    const int w = tid >> 6;

    const float dt = expf(ldt[h]);
    const float Dh = Dp[h];

    // ---- P0: per-state params (r1/r6-proven) + kpad zero pad ----
    if (tid < NN) {
        const int n = tid;
        const float lre = -expf(lnr[h * NN + n]);
        const float lim = img[h * NN + n];
        const float e = expf(lre * dt);
        const float th = lim * dt;
        const float2 A = make_float2(e * cosf(th), e * sinf(th));
        const float den = lre * lre + lim * lim;
        const float2 invL = make_float2(lre / den, -lim / den);
        const float2 am1 = make_float2(A.x - 1.0f, A.y);
        const float2 Bb = cmul(cmul(am1, invL), make_float2(Brp[h*NN+n], Bip[h*NN+n]));
        const float2 CB = cmul(make_float2(Crp[h*NN+n], Cip[h*NN+n]), Bb);
        Abar[n] = A;
        CBb[n] = CB;
        kpad[n] = 0.f;
    }
    // ---- P0b: stage u fp32 chunk-padded (r6-proven) ----
    {
        const float4* u4g = (const float4*)(ug + (size_t)(b * HH + h) * LL);
        float4* uf4 = (float4*)UF;
        #pragma unroll
        for (int r = 0; r < 2; ++r) {
            const int i = tid + 256 * r;
            uf4[(i >> 4) * 17 + (i & 15)] = u4g[i];
        }
    }
    __syncthreads();   // b0

    // ---- P1: W tables. W[n][j] = CB_n*A_n^(j+1). WRE fp32 [n*68+j];
    //          WIM bf16 pairs (j even lo | j odd hi) at [n*33 + j/2]. ----
    {
        const float2 A = Abar[lane];
        const float2 a2 = cmul(A, A), a4 = cmul(a2, a2), a8 = cmul(a4, a4), a16 = cmul(a8, a8);
        float2 pw = cmul(CBb[lane], A);
        for (int i = 0; i < w; ++i) pw = cmul(pw, a16);
        unsigned prevlo = 0;
        #pragma unroll
        for (int jj = 0; jj < 16; ++jj) {
            const int j = 16 * w + jj;
            WRE[lane * 68 + j] = pw.x;
            if ((jj & 1) == 0) prevlo = (unsigned)f2bf(pw.y);
            else WIM[lane * 33 + (j >> 1)] = prevlo | ((unsigned)f2bf(pw.y) << 16);
            pw = cmul(pw, A);
        }
    }
    __syncthreads();   // b1

    // ---- P2a: exact K (wave 0): K[t]=sum_n Re(CB A^t); t>=1 via WRE column t-1 ----
    if (w == 0) {
        float acc = 0.f;
        if (lane == 0) {
            for (int n = 0; n < NN; ++n) acc += CBb[n].x;
        } else {
            const float* col = WRE + (lane - 1);
            #pragma unroll 8
            for (int n = 0; n < NN; ++n) acc += col[n * 68];
        }
        kpad[64 + lane] = acc;
    }
    // ---- P2b: packed 4-step-fused Horner encode (all waves), into registers ----
    // S[c]_n = sum_t A^(63-t) u[c*64+t]; 8 indep groups of 8 steps, A^8 recombine.
    f32x2 Sres[8];
    {
        const float2 Af = Abar[lane];
        const f32x2 A1 = {Af.x, Af.y};
        const f32x2 A2 = cmul2(A1, A1);
        const f32x2 A3 = cmul2(A2, A1);
        const f32x2 A4 = cmul2(A2, A2);
        const f32x2 A8 = cmul2(A4, A4);
        f32x2 P8[8];
        P8[0] = (f32x2){1.f, 0.f};
        #pragma unroll
        for (int k = 1; k < 8; ++k) P8[k] = cmul2(P8[k-1], A8);
        const float4* uf4 = (const float4*)UF;
        #pragma unroll
        for (int k8 = 0; k8 < 8; ++k8) {
            const int c = w + 4 * k8;
            f32x2 sg[8];
            #pragma unroll
            for (int g = 0; g < 8; ++g) {
                const float4 ua = uf4[c * 17 + 2 * g];
                const float4 ub = uf4[c * 17 + 2 * g + 1];
                // fusion 1 (from zero state): t = A3*u0 + A2*u1 + A1*u2 + (u3,0)
                f32x2 t = A3 * ua.x;
                t = pkfma(A2, splat2(ua.y), t);
                t = pkfma(A1, splat2(ua.z), t);
                t[0] += ua.w;
                // fusion 2: sg = A4*t (cmul) + A3*u4 + A2*u5 + A1*u6 + (u7,0)
                f32x2 t2 = A3 * ub.x;
                t2 = pkfma(A2, splat2(ub.y), t2);
                t2 = pkfma(A1, splat2(ub.z), t2);
                t2[0] += ub.w;
                sg[g] = pkfma(splat2(A4[0]), t, pkfma(splat2(A4[1]), swapneg(t), t2));
            }
            f32x2 S = sg[7];
            #pragma unroll
            for (int g = 0; g < 7; ++g)
                S = pkfma(splat2(P8[7-g][0]), sg[g], pkfma(splat2(P8[7-g][1]), swapneg(sg[g]), S));
            Sres[k8] = S;
        }
    }
    // ---- P3: write S to SZ ----
    #pragma unroll
    for (int k8 = 0; k8 < 8; ++k8) {
        const int c = w + 4 * k8;
        SZ[c * 130 + lane]      = Sres[k8][0];
        SZ[c * 130 + 64 + lane] = Sres[k8][1];
    }
    __syncthreads();   // b2: S + kpad ready

    // ---- P4a: scan (wave 0), fp32, in place: SZ[c] := x[c-1] (r6-proven) ----
    if (w == 0) {
        const float2 A = Abar[lane];
        const float2 a2 = cmul(A, A), a4 = cmul(a2, a2), a8 = cmul(a4, a4),
                     a16 = cmul(a8, a8), a32 = cmul(a16, a16), a64 = cmul(a32, a32);
        float xr = 0.f, xi = 0.f;
        for (int c = 0; c < 32; ++c) {
            const float sr = SZ[c * 130 + lane];
            const float si = SZ[c * 130 + 64 + lane];
            SZ[c * 130 + lane]      = xr;
            SZ[c * 130 + 64 + lane] = xi;
            const float nxr = fmaf(a64.x, xr, fmaf(-a64.y, xi, sr));
            xi = fmaf(a64.x, xi, fmaf(a64.y, xr, si));
            xr = nxr;
        }
    }
    // ---- P4b: causal conv, wave-uniform trip. Wave w owns j in [16w,16w+16). ----
    const int jl = lane & 3;
    const int jt = 4 * w + jl;        // j0 = 4*jt
    const int c0 = lane >> 2;         // 0..15
    const int c1 = c0 + 16;
    float a00 = 0.f, a01 = 0.f, a02 = 0.f, a03 = 0.f;
    float a10 = 0.f, a11 = 0.f, a12 = 0.f, a13 = 0.f;
    {
        const float4* u4 = (const float4*)UF;
        const float4* kp4 = (const float4*)kpad;
        const int smax = 4 * w + 4;
        #pragma unroll 4
        for (int s4 = 0; s4 < smax; ++s4) {
            const float4 ua = u4[c0 * 17 + s4];
            const float4 ub = u4[c1 * 17 + s4];
            const float4 Av = kp4[15 + jt - s4];
            const float4 Bv = kp4[16 + jt - s4];
            a00 = fmaf(Bv.x, ua.x, a00); a01 = fmaf(Bv.y, ua.x, a01);
            a02 = fmaf(Bv.z, ua.x, a02); a03 = fmaf(Bv.w, ua.x, a03);
            a10 = fmaf(Bv.x, ub.x, a10); a11 = fmaf(Bv.y, ub.x, a11);
            a12 = fmaf(Bv.z, ub.x, a12); a13 = fmaf(Bv.w, ub.x, a13);
            a00 = fmaf(Av.w, ua.y, a00); a01 = fmaf(Bv.x, ua.y, a01);
            a02 = fmaf(Bv.y, ua.y, a02); a03 = fmaf(Bv.z, ua.y, a03);
            a10 = fmaf(Av.w, ub.y, a10); a11 = fmaf(Bv.x, ub.y, a11);
            a12 = fmaf(Bv.y, ub.y, a12); a13 = fmaf(Bv.z, ub.y, a13);
            a00 = fmaf(Av.z, ua.z, a00); a01 = fmaf(Av.w, ua.z, a01);
            a02 = fmaf(Bv.x, ua.z, a02); a03 = fmaf(Bv.y, ua.z, a03);
            a10 = fmaf(Av.z, ub.z, a10); a11 = fmaf(Av.w, ub.z, a11);
            a12 = fmaf(Bv.x, ub.z, a12); a13 = fmaf(Bv.y, ub.z, a13);
            a00 = fmaf(Av.y, ua.w, a00); a01 = fmaf(Av.z, ua.w, a01);
            a02 = fmaf(Av.w, ua.w, a02); a03 = fmaf(Bv.x, ua.w, a03);
            a10 = fmaf(Av.y, ub.w, a10); a11 = fmaf(Av.z, ub.w, a11);
            a12 = fmaf(Av.w, ub.w, a12); a13 = fmaf(Bv.x, ub.w, a13);
        }
    }
    __syncthreads();   // b3: x ready

    // ---- P5: boundary, packed over j-pairs + epilogue ----
    {
        const int j0 = 4 * jt;
        f32x2 r01 = {a00, a01}, r23 = {a02, a03};
        f32x2 s01 = {a10, a11}, s23 = {a12, a13};
        #pragma unroll 4
        for (int n = 0; n < NN; ++n) {
            const float4 wr = *(const float4*)&WRE[n * 68 + j0];
            const unsigned wa = WIM[n * 33 + (j0 >> 1)];
            const unsigned wb = WIM[n * 33 + (j0 >> 1) + 1];
            const float xr0 = SZ[c0 * 130 + n], xi0 = SZ[c0 * 130 + 64 + n];
            const float xr1 = SZ[c1 * 130 + n], xi1 = SZ[c1 * 130 + 64 + n];
            const f32x2 wr01 = {wr.x, wr.y}, wr23 = {wr.z, wr.w};
            const f32x2 wi01 = {lo2f(wa), hi2f(wa)};
            const f32x2 wi23 = {lo2f(wb), hi2f(wb)};
            r01 = pkfma(wr01, splat2(xr0), r01);
            r23 = pkfma(wr23, splat2(xr0), r23);
            s01 = pkfma(wr01, splat2(xr1), s01);
            s23 = pkfma(wr23, splat2(xr1), s23);
            const float nxi0 = -xi0, nxi1 = -xi1;
            r01 = pkfma(wi01, splat2(nxi0), r01);
            r23 = pkfma(wi23, splat2(nxi0), r23);
            s01 = pkfma(wi01, splat2(nxi1), s01);
            s23 = pkfma(wi23, splat2(nxi1), s23);
        }
        const float4* u4 = (const float4*)UF;
        const float4 uA = u4[c0 * 17 + jt];
        const float4 uB = u4[c1 * 17 + jt];
        float* og = outg + (size_t)(b * HH + h) * LL;
        *(float4*)(og + (size_t)c0 * 64 + j0) =
            make_float4(fmaf(Dh, uA.x, r01[0]), fmaf(Dh, uA.y, r01[1]),
                        fmaf(Dh, uA.z, r23[0]), fmaf(Dh, uA.w, r23[1]));
        *(float4*)(og + (size_t)c1 * 64 + j0) =
            make_float4(fmaf(Dh, uB.x, s01[0]), fmaf(Dh, uB.y, s01[1]),
                        fmaf(Dh, uB.z, s23[0]), fmaf(Dh, uB.w, s23[1]));
    }
}

extern "C" void kernel_launch(void* const* d_in, const int* in_sizes, int n_in,
                              void* d_out, int out_size, void* d_ws, size_t ws_size,
                              hipStream_t stream) {
    (void)in_sizes; (void)n_in; (void)out_size; (void)d_ws; (void)ws_size;
    ssm_kernel7<<<dim3(BB * HH), dim3(256), 0, stream>>>(
        (const float*)d_in[0], (const float*)d_in[1], (const float*)d_in[2],
        (const float*)d_in[3], (const float*)d_in[4], (const float*)d_in[5],
        (const float*)d_in[6], (const float*)d_in[7], (const float*)d_in[8],
        (float*)d_out);
}